// Round 11
// baseline (993.030 us; speedup 1.0000x reference)
//
#include <hip/hip_runtime.h>
#include <hip/hip_cooperative_groups.h>
#include <stdint.h>

namespace cg = cooperative_groups;

#define N_NODES 50000
#define N_EDGES 800000
#define EMB 128
#define NPAD 50176        // padded to multiple of 256 rows (196 mlp chunks x 256)
#define BN_EPS 1e-5f
#define SENT_KEY ((N_NODES << 5) | 21)   // sentinel: zero h-row
#define NODES_PER_XCD 6250               // 50000 / 8
#define XCHUNK 2048
#define NCHUNKS ((N_EDGES + XCHUNK - 1) / XCHUNK)   // 391
#define PBLK 196                          // NPAD / 256

typedef __attribute__((ext_vector_type(8))) short short8;
typedef __attribute__((ext_vector_type(4))) float f32x4;

__device__ __forceinline__ unsigned short f2bf(float f) {
    unsigned int u = __float_as_uint(f);
    u += 0x7fffu + ((u >> 16) & 1u);   // RNE; values finite
    return (unsigned short)(u >> 16);
}
__device__ __forceinline__ float bflo(unsigned int v) { return __uint_as_float(v << 16); }
__device__ __forceinline__ float bfhi(unsigned int v) { return __uint_as_float(v & 0xffff0000u); }
__device__ __forceinline__ unsigned int packbf(float lo, float hi) {
    return (unsigned int)f2bf(lo) | ((unsigned int)f2bf(hi) << 16);
}

// ------- fused prep: embedding + weight transpose/cast + key precompute + dst histogram -------
__global__ void k_prep(const int* __restrict__ x, const float* __restrict__ xe1,
                       const float* __restrict__ xe2, unsigned int* __restrict__ h,
                       const float* __restrict__ W1, const float* __restrict__ W2,
                       unsigned short* __restrict__ w1t, unsigned short* __restrict__ w2t,
                       int* __restrict__ deg,
                       const int* __restrict__ ei, const int* __restrict__ ea,
                       int* __restrict__ keyv) {
    int idx = blockIdx.x * 256 + threadIdx.x;   // [0, (N+1)*64)
    int i = idx >> 6, j = idx & 63;
    if (i < N_NODES) {
        int a = x[2 * i], c = x[2 * i + 1];
        float2 va = *(const float2*)(xe1 + a * EMB + j * 2);
        float2 vb = *(const float2*)(xe2 + c * EMB + j * 2);
        h[i * 64 + j] = packbf(va.x + vb.x, va.y + vb.y);
    } else if (i == N_NODES) {
        h[(size_t)i * 64 + j] = 0u;             // zero sentinel row
    }
    if (idx < 4 * 32768) {                      // weight transpose+cast
        int sec = idx >> 15, q = idx & 32767;
        if (sec < 2) {       // W1[sec]: [128][256] -> w1t[sec][c*128+r]
            int r = q >> 8, c = q & 255;
            w1t[sec * 32768 + c * 128 + r] = f2bf(W1[sec * 32768 + q]);
        } else {             // W2[sec-2]: [256][128] -> w2t[sec-2][c*256+r]
            int s = sec - 2;
            int r = q >> 7, c = q & 127;
            w2t[s * 32768 + c * 256 + r] = f2bf(W2[s * 32768 + q]);
        }
    }
    if (idx < N_EDGES) {                        // packed key + dst histogram
        int2 aa = *(const int2*)(ea + 2 * idx);
        keyv[idx] = (ei[idx] << 5) | (aa.x * 3 + aa.y);
        atomicAdd(&deg[ei[N_EDGES + idx]], 1);
    }
}

// ---------------- CSR region allocation (unordered) + e12@W1 micro-GEMM ----------------
__global__ void k_alloc(const int* __restrict__ deg, int* __restrict__ gcur,
                        int* __restrict__ offs, int* __restrict__ cursor,
                        int* __restrict__ keys, int* __restrict__ bcnt,
                        const float* __restrict__ e1, const float* __restrict__ e2,
                        const float* __restrict__ W1, unsigned short* __restrict__ w1e) {
    __shared__ int wbase[4];
    __shared__ int lc[8];
    int tid = threadIdx.x, lane = tid & 63, wid = tid >> 6;
    if (tid < 8) lc[tid] = 0;
    int i = blockIdx.x * 256 + tid;
    int d = (i < N_NODES) ? deg[i] : 0;
    int pd = (d + 15) & ~15;
    int s = pd;                                  // wave inclusive scan
#pragma unroll
    for (int off = 1; off < 64; off <<= 1) {
        int t = __shfl_up(s, off);
        if (lane >= off) s += t;
    }
    if (lane == 63) wbase[wid] = s;
    __syncthreads();
    if (tid == 0) {                              // one global atomic per block
        int t0 = wbase[0], t1 = wbase[1], t2 = wbase[2], t3 = wbase[3];
        int b = atomicAdd(gcur, t0 + t1 + t2 + t3);
        wbase[0] = b; wbase[1] = b + t0; wbase[2] = b + t0 + t1; wbase[3] = b + t0 + t1 + t2;
    }
    __syncthreads();
    if (i < N_NODES) {
        int o = wbase[wid] + s - pd;             // exclusive within wave
        offs[i] = o;
        cursor[i] = o;
        for (int j = d; j < pd; ++j) keys[o + j] = SENT_KEY;
        int nch = pd >> 4;
        atomicAdd(&lc[nch > 7 ? 7 : nch], 1);
    }
    __syncthreads();
    if (tid < 8) atomicAdd(&bcnt[tid], lc[tid]);

    // e12@W1 micro-GEMM: blocks 0..41 (layer l, combo c); w1e[l][n][32]
    if (blockIdx.x < 42) {
        int l = blockIdx.x / 21, c = blockIdx.x % 21;
        int a0 = c / 3, a1 = c - a0 * 3;
        const float* E1 = e1 + l * 896 + a0 * 128;
        const float* E2 = e2 + l * 384 + a1 * 128;
        const float* w1 = W1 + l * 32768;
        int n = tid;                             // 0..255
        float acc = 0.f;
        for (int k = 0; k < 128; ++k)
            acc = fmaf(E1[k] + E2[k], w1[k * 256 + n], acc);
        w1e[(size_t)l * 8192 + n * 32 + c] = f2bf(acc);
        if (c == 0) {
            for (int cc = 21; cc < 32; ++cc) w1e[(size_t)l * 8192 + n * 32 + cc] = 0;
        }
    }
}

// fill packed keys via keyv gather (XCD-partitioned) + build degree-bucket permutation
__global__ void k_fill(const int* __restrict__ dst, const int* __restrict__ keyv,
                       int* __restrict__ cursor, int* __restrict__ keys,
                       const int* __restrict__ deg, const int* __restrict__ bcnt,
                       int* __restrict__ bcur, int* __restrict__ perm) {
    int xcd = blockIdx.x & 7, chunk = blockIdx.x >> 3;
    int lo = xcd * NODES_PER_XCD, hi = lo + NODES_PER_XCD;
    int e0 = chunk * XCHUNK + threadIdx.x * 4;
#pragma unroll
    for (int it = 0; it < XCHUNK / 1024; ++it) {
        int e = e0 + it * 1024;
        if (e < N_EDGES) {
            int4 d4 = *(const int4*)(dst + e);
            int dv[4] = {d4.x, d4.y, d4.z, d4.w};
#pragma unroll
            for (int q = 0; q < 4; ++q) {
                int d = dv[q];
                if (d >= lo && d < hi) {
                    int p = atomicAdd(&cursor[d], 1);
                    keys[p] = keyv[e + q];
                }
            }
        }
    }
    // degree-bucket counting sort: first PBLK blocks place their 256 nodes
    if (blockIdx.x < PBLK) {
        __shared__ int lcnt[8], gbase[8], tbase[8];
        if (threadIdx.x < 8) lcnt[threadIdx.x] = 0;
        __syncthreads();
        int i = blockIdx.x * 256 + threadIdx.x;
        int b = 0, lrank = 0;
        if (i < N_NODES) {
            int nch = (deg[i] + 15) >> 4;
            b = nch > 7 ? 7 : nch;
            lrank = atomicAdd(&lcnt[b], 1);
        }
        __syncthreads();
        if (threadIdx.x < 8) {
            gbase[threadIdx.x] = atomicAdd(&bcur[threadIdx.x], lcnt[threadIdx.x]);
            int s = 0;
            for (int k = 0; k < threadIdx.x; ++k) s += bcnt[k];
            tbase[threadIdx.x] = s;
        }
        __syncthreads();
        if (i < N_NODES) perm[tbase[b] + gbase[b] + lrank] = i;
    }
}

// ---------------- combo-count build from keys -------------
__global__ __launch_bounds__(256) void k_cnt(const int* __restrict__ deg,
                                             const int* __restrict__ offs,
                                             const int* __restrict__ keys,
                                             unsigned int* __restrict__ cntb32) {
    __shared__ int bins[16][24];
    int tid = threadIdx.x, fl = tid & 15, grp = tid >> 4;
    for (int t = tid; t < 16 * 24; t += 256) ((int*)bins)[t] = 0;
    __syncthreads();
    int node = blockIdx.x * 16 + grp;
    int o = 0, pd = 0;
    if (node < N_NODES) { o = offs[node]; pd = (deg[node] + 15) & ~15; }
    for (int j = fl; j < pd; j += 16)
        atomicAdd(&bins[grp][keys[o + j] & 31], 1);
    __syncthreads();
    if (node < NPAD) {
        int c0 = 0, c1 = 0;
        if (node < N_NODES && fl < 11) {
            c0 = bins[grp][2 * fl]     + (fl == 6 ? 1 : 0);   // self loop -> combo 12
            c1 = bins[grp][2 * fl + 1];
        }
        cntb32[(size_t)node * 16 + fl] = packbf((float)c0, (float)c1);
    }
}

// ---------------- cooperative per-layer pipeline: [agg -> mlp -> bnnorm] x 2 ----------------
// One launch replaces 6: each launch gap (~7us) becomes a grid.sync (~1-2us).
// 256 blocks x 1024 threads, 1 block/CU (145KB LDS). Agg grid-strides 12544 virtual
// waves over 4096 real (fixed 16 waves/CU -- better than the old ~9). Mlp = round-10
// proven body on blocks 0..195. Bnnorm grid-strides, scale/shift recomputed per block.
__global__ __launch_bounds__(1024, 1) void k_layers(
    unsigned int* h,                           // [(N+1)][64] packed bf16x2
    const int* __restrict__ offs, const int* __restrict__ deg,
    const int* __restrict__ keys, const int* __restrict__ perm,
    unsigned int* aggb,                        // [NPAD][64]: agg then h2 (bf16)
    const unsigned short* __restrict__ cntb,   // [NPAD][32] bf16 combo counts
    const unsigned short* __restrict__ w1t_a, const unsigned short* __restrict__ w1e_a,
    const float* __restrict__ b1_a,
    const unsigned short* __restrict__ w2t_a, const float* __restrict__ b2_a,
    float* __restrict__ bnsum_a,
    const float* __restrict__ gm_a, const float* __restrict__ bt_a,
    float4* __restrict__ outf)
{
    cg::grid_group grid = cg::this_grid();
    __shared__ unsigned short w1s[256 * 128];  // 64 KB, XOR-swizzled rows (256 B)
    __shared__ unsigned short w2s[128 * 256];  // 64 KB, XOR-swizzled rows (512 B)
    __shared__ unsigned short w1es[256 * 32];  // 16 KB, linear
    __shared__ float bn[256];
    int tid = threadIdx.x;                     // 0..1023
    int lane = tid & 63;
    int wave = tid >> 6;                       // 0..15
    int quad = lane >> 4, r16 = lane & 15;
    int sel  = (lane >> 5) & 1;
    int srcA = ((lane >> 4) & 1) * 32 + r16;
    int srcB = srcA + 16;
    unsigned short* aggh2 = (unsigned short*)aggb;

    for (int l = 0; l < 2; ++l) {
        const unsigned short* w1t = w1t_a + l * 32768;
        const unsigned short* w1e = w1e_a + l * 8192;
        const float* b1 = b1_a + l * 256;
        const unsigned short* w2t = w2t_a + l * 32768;
        const float* b2 = b2_a + l * 128;
        float* bnsum = bnsum_a + l * 256;

        // ======== phase A: aggregation (all blocks, 4 grid-stride iters) ========
        {
            int rw = blockIdx.x * 16 + wave;           // real wave id 0..4095
            for (int it = 0; it < 4; ++it) {
                int wi = it * 4096 + rw;
                if (wi >= 12544) break;
                int q = (wi & 255) * 49 + (wi >> 8);   // degree-spread bijection
                int slot = q * 4 + quad;               // 4 consecutive sorted slots/wave
                int node = (slot < N_NODES) ? perm[slot] : slot;
                float ax[8] = {0.f, 0.f, 0.f, 0.f, 0.f, 0.f, 0.f, 0.f};
                int o = 0, nch = 0;
                if (node < N_NODES) {
                    o = offs[node];
                    nch = (deg[node] + 15) >> 4;
                    uint4 hv = *(const uint4*)(h + (size_t)node * 64 + r16 * 4);  // self loop
                    ax[0] = bflo(hv.x);  ax[1] = bfhi(hv.x);
                    ax[2] = bflo(hv.y);  ax[3] = bfhi(hv.y);
                    ax[4] = bflo(hv.z);  ax[5] = bfhi(hv.z);
                    ax[6] = bflo(hv.w);  ax[7] = bfhi(hv.w);
                }
                int maxch = nch;
#pragma unroll
                for (int d = 32; d; d >>= 1) maxch = max(maxch, __shfl_xor(maxch, d));
                int key = (0 < nch) ? keys[o + r16] : SENT_KEY;
                for (int c = 0; c < maxch; ++c) {
                    int keyn = (c + 1 < nch) ? keys[o + (c + 1) * 16 + r16] : SENT_KEY;
                    uint4 g[8];
#pragma unroll
                    for (int j = 0; j < 8; ++j) {
                        int kj = __shfl(key, quad * 16 + j);
                        g[j] = *(const uint4*)(h + (size_t)(kj >> 5) * 64 + r16 * 4);
                    }
#pragma unroll
                    for (int j = 0; j < 8; ++j) {
                        uint4 gg = g[j];
                        int kb = __shfl(key, quad * 16 + 8 + j);
                        g[j] = *(const uint4*)(h + (size_t)(kb >> 5) * 64 + r16 * 4);
                        ax[0] += bflo(gg.x);  ax[1] += bfhi(gg.x);
                        ax[2] += bflo(gg.y);  ax[3] += bfhi(gg.y);
                        ax[4] += bflo(gg.z);  ax[5] += bfhi(gg.z);
                        ax[6] += bflo(gg.w);  ax[7] += bfhi(gg.w);
                    }
#pragma unroll
                    for (int j = 0; j < 8; ++j) {
                        uint4 gg = g[j];
                        ax[0] += bflo(gg.x);  ax[1] += bfhi(gg.x);
                        ax[2] += bflo(gg.y);  ax[3] += bfhi(gg.y);
                        ax[4] += bflo(gg.z);  ax[5] += bfhi(gg.z);
                        ax[6] += bflo(gg.w);  ax[7] += bfhi(gg.w);
                    }
                    key = keyn;
                }
                uint4 out;
                out.x = packbf(ax[0], ax[1]); out.y = packbf(ax[2], ax[3]);
                out.z = packbf(ax[4], ax[5]); out.w = packbf(ax[6], ax[7]);
                *(uint4*)(aggb + (size_t)node * 64 + r16 * 4) = out;   // pad rows -> zeros
            }
        }
        __threadfence();
        grid.sync();

        // ======== phase B: MLP (blocks 0..195), weights resident in LDS ========
        if (blockIdx.x < PBLK) {
            if (tid < 256) bn[tid] = 0.f;
            // stage all weights: 9216 16B-chunks over 1024 threads = 9 each
#pragma unroll
            for (int it = 0; it < 9; ++it) {
                int ch = it * 1024 + tid;
                if (ch < 4096) {                       // w1s: 16 chunks/row
                    int row = ch >> 4, sl = ch & 15;
                    uint4 v = *(const uint4*)(w1t + row * 128 + sl * 8);
                    int byte = row * 256 + ((sl * 16) ^ ((row & 7) << 4));
                    *(uint4*)((char*)w1s + byte) = v;
                } else if (ch < 8192) {                // w2s: 32 chunks/row
                    int c = ch - 4096;
                    int row = c >> 5, sl = c & 31;
                    uint4 v = *(const uint4*)(w2t + row * 256 + sl * 8);
                    int byte = row * 512 + ((sl * 16) ^ ((row & 7) << 4));
                    *(uint4*)((char*)w2s + byte) = v;
                } else {                               // w1es: linear, 4 chunks/row
                    int c = ch - 8192;
                    int row = c >> 2, sl = c & 3;
                    *(uint4*)(w1es + row * 32 + sl * 8) = *(const uint4*)(w1e + row * 32 + sl * 8);
                }
            }
            int m0 = (blockIdx.x * 16 + wave) * 16;    // 16 rows per wave
            short8 bagg[5];
#pragma unroll
            for (int c = 0; c < 4; ++c)
                bagg[c] = *(const short8*)(aggh2 + (size_t)(m0 + r16) * 128 + c * 32 + quad * 8);
            bagg[4] = *(const short8*)(cntb + (size_t)(m0 + r16) * 32 + quad * 8);
            float b2v[8];
#pragma unroll
            for (int n = 0; n < 8; ++n) b2v[n] = b2[n * 16 + r16];
            __syncthreads();                           // weights + bn init visible

            f32x4 acc2[8];
#pragma unroll
            for (int n = 0; n < 8; ++n) acc2[n] = (f32x4){0.f, 0.f, 0.f, 0.f};
            int swz = (r16 & 7) << 4;                  // read-side XOR (row&7 == r16&7)
            for (int c2 = 0; c2 < 8; ++c2) {
                unsigned int pk[2][2];
#pragma unroll
                for (int ntl = 0; ntl < 2; ++ntl) {
                    int nt = c2 * 2 + ntl;
                    int row = nt * 16 + r16;
                    short8 aw[5];
#pragma unroll
                    for (int c = 0; c < 4; ++c)
                        aw[c] = *(const short8*)((char*)w1s + row * 256 + ((c * 64 + quad * 16) ^ swz));
                    aw[4] = *(const short8*)(w1es + row * 32 + quad * 8);
                    float4 bv = *(const float4*)(b1 + nt * 16 + quad * 4);
                    f32x4 a1a = {0.f, 0.f, 0.f, 0.f}, a1b = {0.f, 0.f, 0.f, 0.f};
                    a1a = __builtin_amdgcn_mfma_f32_16x16x32_bf16(aw[0], bagg[0], a1a, 0, 0, 0);
                    a1b = __builtin_amdgcn_mfma_f32_16x16x32_bf16(aw[1], bagg[1], a1b, 0, 0, 0);
                    a1a = __builtin_amdgcn_mfma_f32_16x16x32_bf16(aw[2], bagg[2], a1a, 0, 0, 0);
                    a1b = __builtin_amdgcn_mfma_f32_16x16x32_bf16(aw[3], bagg[3], a1b, 0, 0, 0);
                    a1a = __builtin_amdgcn_mfma_f32_16x16x32_bf16(aw[4], bagg[4], a1a, 0, 0, 0);
                    float v0 = a1a[0] + a1b[0] + bv.x; v0 = v0 > 0.f ? v0 : 0.f;
                    float v1 = a1a[1] + a1b[1] + bv.y; v1 = v1 > 0.f ? v1 : 0.f;
                    float v2 = a1a[2] + a1b[2] + bv.z; v2 = v2 > 0.f ? v2 : 0.f;
                    float v3 = a1a[3] + a1b[3] + bv.w; v3 = v3 > 0.f ? v3 : 0.f;
                    pk[ntl][0] = packbf(v0, v1);
                    pk[ntl][1] = packbf(v2, v3);
                }
                short8 a2f;
                {
                    int u0 = __shfl((int)pk[0][0], srcA), w0 = __shfl((int)pk[1][0], srcA);
                    int u1 = __shfl((int)pk[0][1], srcA), w1_ = __shfl((int)pk[1][1], srcA);
                    int u2 = __shfl((int)pk[0][0], srcB), w2_ = __shfl((int)pk[1][0], srcB);
                    int u3 = __shfl((int)pk[0][1], srcB), w3_ = __shfl((int)pk[1][1], srcB);
                    union { int i[4]; short8 s; } a2u;
                    a2u.i[0] = sel ? w0 : u0;
                    a2u.i[1] = sel ? w1_ : u1;
                    a2u.i[2] = sel ? w2_ : u2;
                    a2u.i[3] = sel ? w3_ : u3;
                    a2f = a2u.s;
                }
#pragma unroll
                for (int n = 0; n < 8; ++n) {
                    int row = n * 16 + r16;
                    short8 bw = *(const short8*)((char*)w2s + row * 512 + ((c2 * 64 + quad * 16) ^ swz));
                    acc2[n] = __builtin_amdgcn_mfma_f32_16x16x32_bf16(a2f, bw, acc2[n], 0, 0, 0);
                }
            }
            // epilogue: store h2 + BN partial sums
            float s[8], q[8];
#pragma unroll
            for (int n = 0; n < 8; ++n) { s[n] = 0.f; q[n] = 0.f; }
#pragma unroll
            for (int n = 0; n < 8; ++n)
#pragma unroll
                for (int r = 0; r < 4; ++r) {
                    int row = m0 + quad * 4 + r;
                    float v = acc2[n][r] + b2v[n];
                    if (row < N_NODES) {
                        aggh2[(size_t)row * 128 + n * 16 + r16] = f2bf(v);
                        s[n] += v; q[n] += v * v;
                    }
                }
#pragma unroll
            for (int n = 0; n < 8; ++n) {
                s[n] += __shfl_xor(s[n], 16); q[n] += __shfl_xor(q[n], 16);
                s[n] += __shfl_xor(s[n], 32); q[n] += __shfl_xor(q[n], 32);
            }
            if (quad == 0) {
#pragma unroll
                for (int n = 0; n < 8; ++n) {
                    atomicAdd(&bn[n * 16 + r16], s[n]);
                    atomicAdd(&bn[128 + n * 16 + r16], q[n]);
                }
            }
            __syncthreads();
            if (tid < 256) atomicAdd(&bnsum[tid], bn[tid]);
        }
        __threadfence();
        grid.sync();

        // ======== phase C: BN finalize + apply (all blocks, grid-stride) ========
        {
            if (tid < 128) {
                float mean = bnsum[tid] * (1.f / N_NODES);
                float var  = bnsum[128 + tid] * (1.f / N_NODES) - mean * mean;
                float rstd = rsqrtf(var + BN_EPS);
                float g = gm_a[l * 128 + tid];
                bn[tid]       = g * rstd;                                   // scale
                bn[128 + tid] = bt_a[l * 128 + tid] - mean * g * rstd;      // shift
            }
            __syncthreads();
            int base = blockIdx.x * 1024 + tid;
            for (int it = 0; it < 4; ++it) {
                int idx = it * 262144 + base;          // uint4 units (8 channels each)
                if (idx >= N_NODES * 16) break;
                int p = (idx & 15) * 8;
                uint4 hv = ((const uint4*)aggb)[idx];
                float v0 = bflo(hv.x) * bn[p + 0] + bn[128 + p + 0];
                float v1 = bfhi(hv.x) * bn[p + 1] + bn[128 + p + 1];
                float v2 = bflo(hv.y) * bn[p + 2] + bn[128 + p + 2];
                float v3 = bfhi(hv.y) * bn[p + 3] + bn[128 + p + 3];
                float v4 = bflo(hv.z) * bn[p + 4] + bn[128 + p + 4];
                float v5 = bfhi(hv.z) * bn[p + 5] + bn[128 + p + 5];
                float v6 = bflo(hv.w) * bn[p + 6] + bn[128 + p + 6];
                float v7 = bfhi(hv.w) * bn[p + 7] + bn[128 + p + 7];
                if (l == 0) {
                    v0 = v0 > 0.f ? v0 : 0.f; v1 = v1 > 0.f ? v1 : 0.f;
                    v2 = v2 > 0.f ? v2 : 0.f; v3 = v3 > 0.f ? v3 : 0.f;
                    v4 = v4 > 0.f ? v4 : 0.f; v5 = v5 > 0.f ? v5 : 0.f;
                    v6 = v6 > 0.f ? v6 : 0.f; v7 = v7 > 0.f ? v7 : 0.f;
                    uint4 out;
                    out.x = packbf(v0, v1); out.y = packbf(v2, v3);
                    out.z = packbf(v4, v5); out.w = packbf(v6, v7);
                    ((uint4*)h)[idx] = out;
                } else {
                    outf[2 * idx]     = make_float4(v0, v1, v2, v3);
                    outf[2 * idx + 1] = make_float4(v4, v5, v6, v7);
                }
            }
        }
        if (l == 0) { __threadfence(); grid.sync(); }
    }
}

extern "C" void kernel_launch(void* const* d_in, const int* in_sizes, int n_in,
                              void* d_out, int out_size, void* d_ws, size_t ws_size,
                              hipStream_t stream) {
    const int* x  = (const int*)d_in[0];
    const int* ei = (const int*)d_in[1];
    const int* ea = (const int*)d_in[2];
    // d_in[3] = batch (unused)
    const float* xe1 = (const float*)d_in[4];
    const float* xe2 = (const float*)d_in[5];
    const float* e1  = (const float*)d_in[6];   // [2][7][128]
    const float* e2  = (const float*)d_in[7];   // [2][3][128]
    const float* W1  = (const float*)d_in[8];   // [2][128][256]
    const float* b1  = (const float*)d_in[9];   // [2][256]
    const float* W2  = (const float*)d_in[10];  // [2][256][128]
    const float* b2  = (const float*)d_in[11];  // [2][128]
    const float* gm  = (const float*)d_in[12];  // [2][128]
    const float* bt  = (const float*)d_in[13];  // [2][128]

    char* ws = (char*)d_ws;
    size_t off = 0;
    auto take = [&](size_t bytes) -> char* {
        char* p = ws + off;
        off = (off + bytes + 255) & ~(size_t)255;
        return p;
    };
    unsigned int* h_buf = (unsigned int*)take((size_t)(N_NODES + 1) * 64 * 4); // +1 zero row
    unsigned int* aggb  = (unsigned int*)take((size_t)NPAD * 64 * 4);          // agg, then h2
    unsigned short* w1t = (unsigned short*)take((size_t)2 * 32768 * 2);
    unsigned short* w2t = (unsigned short*)take((size_t)2 * 32768 * 2);
    unsigned short* w1e = (unsigned short*)take((size_t)2 * 8192 * 2);         // [2][256][32]
    unsigned int* cntb32 = (unsigned int*)take((size_t)NPAD * 16 * 4);         // [NPAD][32] bf16
    // combined zero-init region: deg[50000] | bnsum[512] | bmeta[32]
    int* zbuf   = (int*)take((size_t)(N_NODES + 512 + 32) * 4);
    int* deg    = zbuf;
    float* bnsum = (float*)(zbuf + N_NODES);            // [2][256]
    int* bmeta  = zbuf + N_NODES + 512;                 // bcnt[8], bcur[8], gcur[1]
    int* offs   = (int*)take((size_t)(N_NODES + 1) * 4);
    int* cursor = (int*)take((size_t)N_NODES * 4);
    int* keys   = (int*)take((size_t)(N_EDGES + N_NODES * 16) * 4);
    int* keyv   = (int*)take((size_t)N_EDGES * 4);
    int* perm   = (int*)take((size_t)N_NODES * 4);
    int* bcnt = bmeta, *bcur = bmeta + 8, *gcur = bmeta + 16;

    hipMemsetAsync(zbuf, 0, (size_t)(N_NODES + 512 + 32) * 4, stream);
    k_prep<<<((N_NODES + 1) * 64 + 255) / 256, 256, 0, stream>>>(x, xe1, xe2, h_buf,
                                                                 W1, W2, w1t, w2t, deg,
                                                                 ei, ea, keyv);
    k_alloc<<<PBLK, 256, 0, stream>>>(deg, gcur, offs, cursor, keys, bcnt,
                                      e1, e2, W1, w1e);
    k_fill<<<8 * NCHUNKS, 256, 0, stream>>>(ei + N_EDGES, keyv, cursor, keys,
                                            deg, bcnt, bcur, perm);
    k_cnt<<<NPAD / 16, 256, 0, stream>>>(deg, offs, keys, cntb32);

    const unsigned short* cntb_us = (const unsigned short*)cntb32;
    float4* outf = (float4*)d_out;
    void* kargs[] = {
        (void*)&h_buf, (void*)&offs, (void*)&deg, (void*)&keys, (void*)&perm,
        (void*)&aggb, (void*)&cntb_us,
        (void*)&w1t, (void*)&w1e, (void*)&b1,
        (void*)&w2t, (void*)&b2,
        (void*)&bnsum, (void*)&gm, (void*)&bt, (void*)&outf
    };
    hipLaunchCooperativeKernel((void*)k_layers, dim3(256), dim3(1024), kargs, 0, stream);
}

// Round 12
// 416.458 us; speedup vs baseline: 2.3845x; 2.3845x over previous
//
#include <hip/hip_runtime.h>
#include <stdint.h>

#define N_NODES 50000
#define N_EDGES 800000
#define EMB 128
#define NPAD 50176        // padded to multiple of 256 rows (196 mlp blocks x 256)
#define BN_EPS 1e-5f
#define SENT_KEY ((N_NODES << 5) | 21)   // sentinel: zero h-row
#define NODES_PER_XCD 6250               // 50000 / 8
#define XCHUNK 2048
#define NCHUNKS ((N_EDGES + XCHUNK - 1) / XCHUNK)   // 391
#define PBLK 196                          // NPAD / 256

typedef __attribute__((ext_vector_type(8))) short short8;
typedef __attribute__((ext_vector_type(4))) float f32x4;

__device__ __forceinline__ unsigned short f2bf(float f) {
    unsigned int u = __float_as_uint(f);
    u += 0x7fffu + ((u >> 16) & 1u);   // RNE; values finite
    return (unsigned short)(u >> 16);
}
__device__ __forceinline__ float bflo(unsigned int v) { return __uint_as_float(v << 16); }
__device__ __forceinline__ float bfhi(unsigned int v) { return __uint_as_float(v & 0xffff0000u); }
__device__ __forceinline__ unsigned int packbf(float lo, float hi) {
    return (unsigned int)f2bf(lo) | ((unsigned int)f2bf(hi) << 16);
}

// ------- fused prep: embedding + weight transpose/cast + key precompute + dst histogram -------
// deg/bnsum/bmeta are pre-zeroed by one hipMemsetAsync before this kernel.
__global__ void k_prep(const int* __restrict__ x, const float* __restrict__ xe1,
                       const float* __restrict__ xe2, unsigned int* __restrict__ h,
                       const float* __restrict__ W1, const float* __restrict__ W2,
                       unsigned short* __restrict__ w1t, unsigned short* __restrict__ w2t,
                       int* __restrict__ deg,
                       const int* __restrict__ ei, const int* __restrict__ ea,
                       int* __restrict__ keyv) {
    int idx = blockIdx.x * 256 + threadIdx.x;   // [0, (N+1)*64)
    int i = idx >> 6, j = idx & 63;
    if (i < N_NODES) {
        int a = x[2 * i], c = x[2 * i + 1];
        float2 va = *(const float2*)(xe1 + a * EMB + j * 2);
        float2 vb = *(const float2*)(xe2 + c * EMB + j * 2);
        h[i * 64 + j] = packbf(va.x + vb.x, va.y + vb.y);
    } else if (i == N_NODES) {
        h[(size_t)i * 64 + j] = 0u;             // zero sentinel row
    }
    if (idx < 4 * 32768) {                      // weight transpose+cast
        int sec = idx >> 15, q = idx & 32767;
        if (sec < 2) {       // W1[sec]: [128][256] -> w1t[sec][c*128+r]
            int r = q >> 8, c = q & 255;
            w1t[sec * 32768 + c * 128 + r] = f2bf(W1[sec * 32768 + q]);
        } else {             // W2[sec-2]: [256][128] -> w2t[sec-2][c*256+r]
            int s = sec - 2;
            int r = q >> 7, c = q & 127;
            w2t[s * 32768 + c * 256 + r] = f2bf(W2[s * 32768 + q]);
        }
    }
    if (idx < N_EDGES) {                        // packed key + dst histogram
        int2 aa = *(const int2*)(ea + 2 * idx);
        keyv[idx] = (ei[idx] << 5) | (aa.x * 3 + aa.y);
        atomicAdd(&deg[ei[N_EDGES + idx]], 1);
    }
}

// ---------------- CSR region allocation (unordered) + e12@W1 micro-GEMM ----------------
__global__ void k_alloc(const int* __restrict__ deg, int* __restrict__ gcur,
                        int* __restrict__ offs, int* __restrict__ cursor,
                        int* __restrict__ keys, int* __restrict__ bcnt,
                        const float* __restrict__ e1, const float* __restrict__ e2,
                        const float* __restrict__ W1, unsigned short* __restrict__ w1e) {
    __shared__ int wbase[4];
    __shared__ int lc[8];
    int tid = threadIdx.x, lane = tid & 63, wid = tid >> 6;
    if (tid < 8) lc[tid] = 0;
    int i = blockIdx.x * 256 + tid;
    int d = (i < N_NODES) ? deg[i] : 0;
    int pd = (d + 15) & ~15;
    int s = pd;                                  // wave inclusive scan
#pragma unroll
    for (int off = 1; off < 64; off <<= 1) {
        int t = __shfl_up(s, off);
        if (lane >= off) s += t;
    }
    if (lane == 63) wbase[wid] = s;
    __syncthreads();
    if (tid == 0) {                              // one global atomic per block
        int t0 = wbase[0], t1 = wbase[1], t2 = wbase[2], t3 = wbase[3];
        int b = atomicAdd(gcur, t0 + t1 + t2 + t3);
        wbase[0] = b; wbase[1] = b + t0; wbase[2] = b + t0 + t1; wbase[3] = b + t0 + t1 + t2;
    }
    __syncthreads();
    if (i < N_NODES) {
        int o = wbase[wid] + s - pd;             // exclusive within wave
        offs[i] = o;
        cursor[i] = o;
        for (int j = d; j < pd; ++j) keys[o + j] = SENT_KEY;
        int nch = pd >> 4;
        atomicAdd(&lc[nch > 7 ? 7 : nch], 1);
    }
    __syncthreads();
    if (tid < 8) atomicAdd(&bcnt[tid], lc[tid]);

    // e12@W1 micro-GEMM: blocks 0..41 (layer l, combo c); w1e[l][n][32]
    if (blockIdx.x < 42) {
        int l = blockIdx.x / 21, c = blockIdx.x % 21;
        int a0 = c / 3, a1 = c - a0 * 3;
        const float* E1 = e1 + l * 896 + a0 * 128;
        const float* E2 = e2 + l * 384 + a1 * 128;
        const float* w1 = W1 + l * 32768;
        int n = tid;                             // 0..255
        float acc = 0.f;
        for (int k = 0; k < 128; ++k)
            acc = fmaf(E1[k] + E2[k], w1[k * 256 + n], acc);
        w1e[(size_t)l * 8192 + n * 32 + c] = f2bf(acc);
        if (c == 0) {
            for (int cc = 21; cc < 32; ++cc) w1e[(size_t)l * 8192 + n * 32 + cc] = 0;
        }
    }
}

// fill packed keys via keyv gather (XCD-partitioned) + build degree-bucket permutation
__global__ void k_fill(const int* __restrict__ dst, const int* __restrict__ keyv,
                       int* __restrict__ cursor, int* __restrict__ keys,
                       const int* __restrict__ deg, const int* __restrict__ bcnt,
                       int* __restrict__ bcur, int* __restrict__ perm) {
    int xcd = blockIdx.x & 7, chunk = blockIdx.x >> 3;
    int lo = xcd * NODES_PER_XCD, hi = lo + NODES_PER_XCD;
    int e0 = chunk * XCHUNK + threadIdx.x * 4;
#pragma unroll
    for (int it = 0; it < XCHUNK / 1024; ++it) {
        int e = e0 + it * 1024;
        if (e < N_EDGES) {
            int4 d4 = *(const int4*)(dst + e);
            int dv[4] = {d4.x, d4.y, d4.z, d4.w};
#pragma unroll
            for (int q = 0; q < 4; ++q) {
                int d = dv[q];
                if (d >= lo && d < hi) {
                    int p = atomicAdd(&cursor[d], 1);
                    keys[p] = keyv[e + q];
                }
            }
        }
    }
    // degree-bucket counting sort: first PBLK blocks place their 256 nodes
    if (blockIdx.x < PBLK) {
        __shared__ int lcnt[8], gbase[8], tbase[8];
        if (threadIdx.x < 8) lcnt[threadIdx.x] = 0;
        __syncthreads();
        int i = blockIdx.x * 256 + threadIdx.x;
        int b = 0, lrank = 0;
        if (i < N_NODES) {
            int nch = (deg[i] + 15) >> 4;
            b = nch > 7 ? 7 : nch;
            lrank = atomicAdd(&lcnt[b], 1);
        }
        __syncthreads();
        if (threadIdx.x < 8) {
            gbase[threadIdx.x] = atomicAdd(&bcur[threadIdx.x], lcnt[threadIdx.x]);
            int s = 0;
            for (int k = 0; k < threadIdx.x; ++k) s += bcnt[k];
            tbase[threadIdx.x] = s;
        }
        __syncthreads();
        if (i < N_NODES) perm[tbase[b] + gbase[b] + lrank] = i;
    }
}

// ---------------- combo-count build from keys -------------
__global__ __launch_bounds__(256) void k_cnt(const int* __restrict__ deg,
                                             const int* __restrict__ offs,
                                             const int* __restrict__ keys,
                                             unsigned int* __restrict__ cntb32) {
    __shared__ int bins[16][24];
    int tid = threadIdx.x, fl = tid & 15, grp = tid >> 4;
    for (int t = tid; t < 16 * 24; t += 256) ((int*)bins)[t] = 0;
    __syncthreads();
    int node = blockIdx.x * 16 + grp;
    int o = 0, pd = 0;
    if (node < N_NODES) { o = offs[node]; pd = (deg[node] + 15) & ~15; }
    for (int j = fl; j < pd; j += 16)
        atomicAdd(&bins[grp][keys[o + j] & 31], 1);
    __syncthreads();
    if (node < NPAD) {
        int c0 = 0, c1 = 0;
        if (node < N_NODES && fl < 11) {
            c0 = bins[grp][2 * fl]     + (fl == 6 ? 1 : 0);   // self loop -> combo 12
            c1 = bins[grp][2 * fl + 1];
        }
        cntb32[(size_t)node * 16 + fl] = packbf((float)c0, (float)c1);
    }
}

// ---------------- aggregation: PURE gather-sum -------------
// No LDS, VGPR<=64 -> declare 8 waves/EU so occupancy cap is 32 waves/CU
// (round-10 measured ~25-30% occupancy; latency-bound gather wants max TLP).
__global__ __launch_bounds__(256, 8) void k_agg(
    const unsigned int* __restrict__ h,        // [(N+1)][64] packed bf16x2 (row N = zeros)
    const int* __restrict__ offs,              // [N] padded region starts (unordered)
    const int* __restrict__ deg,               // [N] real degrees
    const int* __restrict__ keys,              // padded packed keys
    const int* __restrict__ perm,              // degree-bucket-sorted node ids
    unsigned int* __restrict__ agg)            // [NPAD][64] packed bf16x2
{
    int wave = threadIdx.x >> 6, lane = threadIdx.x & 63;
    int sub = lane >> 4, fl = lane & 15;
    int wi = blockIdx.x * 4 + wave;              // global wave id in [0, 12544)
    int q = (wi & 255) * 49 + (wi >> 8);         // bijection (12544 = 256*49): spread degrees
    int slot = q * 4 + sub;                      // wave keeps 4 CONSECUTIVE sorted slots
    int node = (slot < N_NODES) ? perm[slot] : slot;
    float ax[8] = {0.f, 0.f, 0.f, 0.f, 0.f, 0.f, 0.f, 0.f};
    int o = 0, nch = 0;
    if (node < N_NODES) {
        o = offs[node];
        nch = (deg[node] + 15) >> 4;
        uint4 hv = *(const uint4*)(h + (size_t)node * 64 + fl * 4);   // self loop
        ax[0] = bflo(hv.x);  ax[1] = bfhi(hv.x);
        ax[2] = bflo(hv.y);  ax[3] = bfhi(hv.y);
        ax[4] = bflo(hv.z);  ax[5] = bfhi(hv.z);
        ax[6] = bflo(hv.w);  ax[7] = bfhi(hv.w);
    }
    int maxch = nch;
#pragma unroll
    for (int d = 32; d; d >>= 1) maxch = max(maxch, __shfl_xor(maxch, d));
    int key = (0 < nch) ? keys[o + fl] : SENT_KEY;
    for (int c = 0; c < maxch; ++c) {
        int keyn = (c + 1 < nch) ? keys[o + (c + 1) * 16 + fl] : SENT_KEY;
        uint4 g[8];
#pragma unroll
        for (int j = 0; j < 8; ++j) {
            int kj = __shfl(key, sub * 16 + j);
            g[j] = *(const uint4*)(h + (size_t)(kj >> 5) * 64 + fl * 4);
        }
#pragma unroll
        for (int j = 0; j < 8; ++j) {
            uint4 gg = g[j];
            int kb = __shfl(key, sub * 16 + 8 + j);
            g[j] = *(const uint4*)(h + (size_t)(kb >> 5) * 64 + fl * 4);
            ax[0] += bflo(gg.x);  ax[1] += bfhi(gg.x);
            ax[2] += bflo(gg.y);  ax[3] += bfhi(gg.y);
            ax[4] += bflo(gg.z);  ax[5] += bfhi(gg.z);
            ax[6] += bflo(gg.w);  ax[7] += bfhi(gg.w);
        }
#pragma unroll
        for (int j = 0; j < 8; ++j) {
            uint4 gg = g[j];
            ax[0] += bflo(gg.x);  ax[1] += bfhi(gg.x);
            ax[2] += bflo(gg.y);  ax[3] += bfhi(gg.y);
            ax[4] += bflo(gg.z);  ax[5] += bfhi(gg.z);
            ax[6] += bflo(gg.w);  ax[7] += bfhi(gg.w);
        }
        key = keyn;
    }
    {
        uint4 out;
        out.x = packbf(ax[0], ax[1]); out.y = packbf(ax[2], ax[3]);
        out.z = packbf(ax[4], ax[5]); out.w = packbf(ax[6], ax[7]);
        *(uint4*)(agg + (size_t)node * 64 + fl * 4) = out;   // pad rows -> zeros
    }
}

// ---------------- fused MLP + BN stats: ALL weights resident in LDS (144 KB), 1 barrier ----------------
// 1024-thread blocks (16 waves x 16 rows = 256 rows/block, grid 196). Stage w1t/w2t/w1e
// once with XOR-swizzle (byte ^= (row&7)<<4 on w1s/w2s -> conflict-free b128 reads),
// then waves run barrier-free: per-wave 8 c2 sub-blocks of GEMM1 -> shuffle-convert ->
// GEMM2. Round-9 lesson: per-c2 staging round-robin = naked load latency between
// barriers; resident weights remove it entirely.
__global__ __launch_bounds__(1024, 1) void k_mlp(
    unsigned short* aggh2,                     // [NPAD][128] bf16 in, [N][128] bf16 out
    const unsigned short* __restrict__ cntb,   // [NPAD][32] bf16 combo counts
    const unsigned short* __restrict__ w1t,    // [256][128]  (W1 transposed: [n][k])
    const unsigned short* __restrict__ w1e,    // [256][32]   (e12@W1 transposed: [n][c])
    const float* __restrict__ b1,              // [256]
    const unsigned short* __restrict__ w2t,    // [128][256]  (W2 transposed: [n][k])
    const float* __restrict__ b2,              // [128]
    float* __restrict__ bnsum)                 // [256]: cols 0..127 sum, 128..255 sumsq
{
    __shared__ unsigned short w1s[256 * 128];  // 64 KB, XOR-swizzled rows (256 B)
    __shared__ unsigned short w2s[128 * 256];  // 64 KB, XOR-swizzled rows (512 B)
    __shared__ unsigned short w1es[256 * 32];  // 16 KB, linear
    __shared__ float bn[256];
    int tid = threadIdx.x;                     // 0..1023
    int lane = tid & 63;
    int wave = tid >> 6;                       // 0..15
    int quad = lane >> 4, r16 = lane & 15;
    int m0 = (blockIdx.x * 16 + wave) * 16;    // 16 rows per wave
    int sel  = (lane >> 5) & 1;
    int srcA = ((lane >> 4) & 1) * 32 + r16;
    int srcB = srcA + 16;
    if (tid < 256) bn[tid] = 0.f;

    // ---- stage all weights: 9216 16B-chunks over 1024 threads = 9 each ----
#pragma unroll
    for (int it = 0; it < 9; ++it) {
        int ch = it * 1024 + tid;
        if (ch < 4096) {                       // w1s: row=ch>>4 (16 chunks/row)
            int row = ch >> 4, sl = ch & 15;
            uint4 v = *(const uint4*)(w1t + row * 128 + sl * 8);
            int byte = row * 256 + ((sl * 16) ^ ((row & 7) << 4));
            *(uint4*)((char*)w1s + byte) = v;
        } else if (ch < 8192) {                // w2s: 32 chunks/row
            int c = ch - 4096;
            int row = c >> 5, sl = c & 31;
            uint4 v = *(const uint4*)(w2t + row * 256 + sl * 8);
            int byte = row * 512 + ((sl * 16) ^ ((row & 7) << 4));
            *(uint4*)((char*)w2s + byte) = v;
        } else {                               // w1es: linear, 4 chunks/row
            int c = ch - 8192;
            int row = c >> 2, sl = c & 3;
            *(uint4*)(w1es + row * 32 + sl * 8) = *(const uint4*)(w1e + row * 32 + sl * 8);
        }
    }

    // agg B-frags (GEMM1 swapped): B[k=quad*8+j][node=r16]; chunk 4 = cnt (K 128..159)
    short8 bagg[5];
#pragma unroll
    for (int c = 0; c < 4; ++c)
        bagg[c] = *(const short8*)(aggh2 + (size_t)(m0 + r16) * 128 + c * 32 + quad * 8);
    bagg[4] = *(const short8*)(cntb + (size_t)(m0 + r16) * 32 + quad * 8);

    float b2v[8];
#pragma unroll
    for (int n = 0; n < 8; ++n) b2v[n] = b2[n * 16 + r16];

    __syncthreads();                           // weights + bn init visible

    f32x4 acc2[8];
#pragma unroll
    for (int n = 0; n < 8; ++n) acc2[n] = (f32x4){0.f, 0.f, 0.f, 0.f};

    int swz = (r16 & 7) << 4;                  // read-side XOR (row&7 == r16&7)
    for (int c2 = 0; c2 < 8; ++c2) {
        unsigned int pk[2][2];                 // [ntl][dword]
#pragma unroll
        for (int ntl = 0; ntl < 2; ++ntl) {
            int nt = c2 * 2 + ntl;
            int row = nt * 16 + r16;
            short8 aw[5];
#pragma unroll
            for (int c = 0; c < 4; ++c)
                aw[c] = *(const short8*)((char*)w1s + row * 256 + ((c * 64 + quad * 16) ^ swz));
            aw[4] = *(const short8*)(w1es + row * 32 + quad * 8);
            float4 bv = *(const float4*)(b1 + nt * 16 + quad * 4);
            f32x4 a1a = {0.f, 0.f, 0.f, 0.f}, a1b = {0.f, 0.f, 0.f, 0.f};
            a1a = __builtin_amdgcn_mfma_f32_16x16x32_bf16(aw[0], bagg[0], a1a, 0, 0, 0);
            a1b = __builtin_amdgcn_mfma_f32_16x16x32_bf16(aw[1], bagg[1], a1b, 0, 0, 0);
            a1a = __builtin_amdgcn_mfma_f32_16x16x32_bf16(aw[2], bagg[2], a1a, 0, 0, 0);
            a1b = __builtin_amdgcn_mfma_f32_16x16x32_bf16(aw[3], bagg[3], a1b, 0, 0, 0);
            a1a = __builtin_amdgcn_mfma_f32_16x16x32_bf16(aw[4], bagg[4], a1a, 0, 0, 0);
            float v0 = a1a[0] + a1b[0] + bv.x; v0 = v0 > 0.f ? v0 : 0.f;
            float v1 = a1a[1] + a1b[1] + bv.y; v1 = v1 > 0.f ? v1 : 0.f;
            float v2 = a1a[2] + a1b[2] + bv.z; v2 = v2 > 0.f ? v2 : 0.f;
            float v3 = a1a[3] + a1b[3] + bv.w; v3 = v3 > 0.f ? v3 : 0.f;
            pk[ntl][0] = packbf(v0, v1);
            pk[ntl][1] = packbf(v2, v3);
        }
        short8 a2f;
        {
            int u0 = __shfl((int)pk[0][0], srcA), w0 = __shfl((int)pk[1][0], srcA);
            int u1 = __shfl((int)pk[0][1], srcA), w1_ = __shfl((int)pk[1][1], srcA);
            int u2 = __shfl((int)pk[0][0], srcB), w2_ = __shfl((int)pk[1][0], srcB);
            int u3 = __shfl((int)pk[0][1], srcB), w3_ = __shfl((int)pk[1][1], srcB);
            union { int i[4]; short8 s; } a2u;
            a2u.i[0] = sel ? w0 : u0;
            a2u.i[1] = sel ? w1_ : u1;
            a2u.i[2] = sel ? w2_ : u2;
            a2u.i[3] = sel ? w3_ : u3;
            a2f = a2u.s;
        }
#pragma unroll
        for (int n = 0; n < 8; ++n) {
            int row = n * 16 + r16;
            short8 bw = *(const short8*)((char*)w2s + row * 512 + ((c2 * 64 + quad * 16) ^ swz));
            acc2[n] = __builtin_amdgcn_mfma_f32_16x16x32_bf16(a2f, bw, acc2[n], 0, 0, 0);
        }
    }
    // epilogue: store h2 + accumulate per-lane BN partial sums (fp32, rows < N only)
    float s[8], q[8];
#pragma unroll
    for (int n = 0; n < 8; ++n) { s[n] = 0.f; q[n] = 0.f; }
#pragma unroll
    for (int n = 0; n < 8; ++n)
#pragma unroll
        for (int r = 0; r < 4; ++r) {
            int row = m0 + quad * 4 + r;
            float v = acc2[n][r] + b2v[n];
            if (row < N_NODES) {
                aggh2[(size_t)row * 128 + n * 16 + r16] = f2bf(v);
                s[n] += v; q[n] += v * v;
            }
        }
    // reduce over quads (same col set): lanes differ in bits 4,5
#pragma unroll
    for (int n = 0; n < 8; ++n) {
        s[n] += __shfl_xor(s[n], 16); q[n] += __shfl_xor(q[n], 16);
        s[n] += __shfl_xor(s[n], 32); q[n] += __shfl_xor(q[n], 32);
    }
    if (quad == 0) {          // 16 lanes per wave x 16 waves -> LDS atomics
#pragma unroll
        for (int n = 0; n < 8; ++n) {
            atomicAdd(&bn[n * 16 + r16], s[n]);
            atomicAdd(&bn[128 + n * 16 + r16], q[n]);
        }
    }
    __syncthreads();
    if (tid < 256) atomicAdd(&bnsum[tid], bn[tid]);   // one device atomic per col
}

// ---------------- BN finalize + apply (fused; +relu for layer 0 -> bf16 h; layer 1 -> fp32 out) ----------------
__global__ void k_bnnorm(const uint4* __restrict__ h2, const float* __restrict__ bnsum,
                         const float* __restrict__ gamma, const float* __restrict__ beta,
                         uint4* __restrict__ outb, float4* __restrict__ outf, int mode) {
    __shared__ float ab[256];
    int tid = threadIdx.x;
    if (tid < 128) {
        float mean = bnsum[tid] * (1.f / N_NODES);
        float var  = bnsum[128 + tid] * (1.f / N_NODES) - mean * mean;
        float rstd = rsqrtf(var + BN_EPS);
        float g = gamma[tid];
        ab[tid]       = g * rstd;                       // scale
        ab[128 + tid] = beta[tid] - mean * g * rstd;    // shift
    }
    __syncthreads();
    int idx = blockIdx.x * 256 + tid;          // [0, N*16) uint4 units (8 channels each)
    if (idx >= N_NODES * 16) return;
    int p = (idx & 15) * 8;                    // starting channel
    uint4 hv = h2[idx];
    float v0 = bflo(hv.x) * ab[p + 0] + ab[128 + p + 0];
    float v1 = bfhi(hv.x) * ab[p + 1] + ab[128 + p + 1];
    float v2 = bflo(hv.y) * ab[p + 2] + ab[128 + p + 2];
    float v3 = bfhi(hv.y) * ab[p + 3] + ab[128 + p + 3];
    float v4 = bflo(hv.z) * ab[p + 4] + ab[128 + p + 4];
    float v5 = bfhi(hv.z) * ab[p + 5] + ab[128 + p + 5];
    float v6 = bflo(hv.w) * ab[p + 6] + ab[128 + p + 6];
    float v7 = bfhi(hv.w) * ab[p + 7] + ab[128 + p + 7];
    if (mode == 0) {
        v0 = v0 > 0.f ? v0 : 0.f; v1 = v1 > 0.f ? v1 : 0.f;
        v2 = v2 > 0.f ? v2 : 0.f; v3 = v3 > 0.f ? v3 : 0.f;
        v4 = v4 > 0.f ? v4 : 0.f; v5 = v5 > 0.f ? v5 : 0.f;
        v6 = v6 > 0.f ? v6 : 0.f; v7 = v7 > 0.f ? v7 : 0.f;
        uint4 out;
        out.x = packbf(v0, v1); out.y = packbf(v2, v3);
        out.z = packbf(v4, v5); out.w = packbf(v6, v7);
        outb[idx] = out;
    } else {
        outf[2 * idx]     = make_float4(v0, v1, v2, v3);
        outf[2 * idx + 1] = make_float4(v4, v5, v6, v7);
    }
}

extern "C" void kernel_launch(void* const* d_in, const int* in_sizes, int n_in,
                              void* d_out, int out_size, void* d_ws, size_t ws_size,
                              hipStream_t stream) {
    const int* x  = (const int*)d_in[0];
    const int* ei = (const int*)d_in[1];
    const int* ea = (const int*)d_in[2];
    // d_in[3] = batch (unused)
    const float* xe1 = (const float*)d_in[4];
    const float* xe2 = (const float*)d_in[5];
    const float* e1  = (const float*)d_in[6];   // [2][7][128]
    const float* e2  = (const float*)d_in[7];   // [2][3][128]
    const float* W1  = (const float*)d_in[8];   // [2][128][256]
    const float* b1  = (const float*)d_in[9];   // [2][256]
    const float* W2  = (const float*)d_in[10];  // [2][256][128]
    const float* b2  = (const float*)d_in[11];  // [2][128]
    const float* gm  = (const float*)d_in[12];  // [2][128]
    const float* bt  = (const float*)d_in[13];  // [2][128]

    char* ws = (char*)d_ws;
    size_t off = 0;
    auto take = [&](size_t bytes) -> char* {
        char* p = ws + off;
        off = (off + bytes + 255) & ~(size_t)255;
        return p;
    };
    unsigned int* h_buf = (unsigned int*)take((size_t)(N_NODES + 1) * 64 * 4); // +1 zero row
    unsigned int* aggb  = (unsigned int*)take((size_t)NPAD * 64 * 4);          // agg, then h2
    unsigned short* w1t = (unsigned short*)take((size_t)2 * 32768 * 2);
    unsigned short* w2t = (unsigned short*)take((size_t)2 * 32768 * 2);
    unsigned short* w1e = (unsigned short*)take((size_t)2 * 8192 * 2);         // [2][256][32]
    unsigned int* cntb32 = (unsigned int*)take((size_t)NPAD * 16 * 4);         // [NPAD][32] bf16
    // combined zero-init region: deg[50000] | bnsum[512] | bmeta[32]
    int* zbuf   = (int*)take((size_t)(N_NODES + 512 + 32) * 4);
    int* deg    = zbuf;
    float* bnsum = (float*)(zbuf + N_NODES);            // [2][256]
    int* bmeta  = zbuf + N_NODES + 512;                 // bcnt[8], bcur[8], gcur[1]
    int* offs   = (int*)take((size_t)(N_NODES + 1) * 4);
    int* cursor = (int*)take((size_t)N_NODES * 4);
    int* keys   = (int*)take((size_t)(N_EDGES + N_NODES * 16) * 4);
    int* keyv   = (int*)take((size_t)N_EDGES * 4);
    int* perm   = (int*)take((size_t)N_NODES * 4);
    int* bcnt = bmeta, *bcur = bmeta + 8, *gcur = bmeta + 16;

    hipMemsetAsync(zbuf, 0, (size_t)(N_NODES + 512 + 32) * 4, stream);
    k_prep<<<((N_NODES + 1) * 64 + 255) / 256, 256, 0, stream>>>(x, xe1, xe2, h_buf,
                                                                 W1, W2, w1t, w2t, deg,
                                                                 ei, ea, keyv);
    k_alloc<<<PBLK, 256, 0, stream>>>(deg, gcur, offs, cursor, keys, bcnt,
                                      e1, e2, W1, w1e);
    k_fill<<<8 * NCHUNKS, 256, 0, stream>>>(ei + N_EDGES, keyv, cursor, keys,
                                            deg, bcnt, bcur, perm);
    k_cnt<<<NPAD / 16, 256, 0, stream>>>(deg, offs, keys, cntb32);

    for (int l = 0; l < 2; ++l) {
        k_agg<<<NPAD / 16, 256, 0, stream>>>(h_buf, offs, deg, keys, perm, aggb);
        k_mlp<<<NPAD / 256, 1024, 0, stream>>>((unsigned short*)aggb, (const unsigned short*)cntb32,
                                               w1t + l * 32768, w1e + l * 8192, b1 + l * 256,
                                               w2t + l * 32768, b2 + l * 128, bnsum + l * 256);
        k_bnnorm<<<(N_NODES * 16 + 255) / 256, 256, 0, stream>>>((const uint4*)aggb, bnsum + l * 256,
                                                                 gm + l * 128, bt + l * 128,
                                                                 (uint4*)h_buf, (float4*)d_out, l);
    }
}

// Round 13
// 316.387 us; speedup vs baseline: 3.1387x; 1.3163x over previous
//
#include <hip/hip_runtime.h>
#include <stdint.h>

#define N_NODES 50000
#define N_EDGES 800000
#define EMB 128
#define NPAD 50176        // padded to multiple of 256 rows (196 mlp blocks x 256)
#define BN_EPS 1e-5f
#define SENT_KEY ((N_NODES << 5) | 21)   // sentinel: zero h-row
#define NODES_PER_XCD 6250               // 50000 / 8
#define XCHUNK 2048
#define NCHUNKS ((N_EDGES + XCHUNK - 1) / XCHUNK)   // 391
#define PBLK 196                          // NPAD / 256

typedef __attribute__((ext_vector_type(8))) short short8;
typedef __attribute__((ext_vector_type(4))) float f32x4;

__device__ __forceinline__ unsigned short f2bf(float f) {
    unsigned int u = __float_as_uint(f);
    u += 0x7fffu + ((u >> 16) & 1u);   // RNE; values finite
    return (unsigned short)(u >> 16);
}
__device__ __forceinline__ float bflo(unsigned int v) { return __uint_as_float(v << 16); }
__device__ __forceinline__ float bfhi(unsigned int v) { return __uint_as_float(v & 0xffff0000u); }
__device__ __forceinline__ unsigned int packbf(float lo, float hi) {
    return (unsigned int)f2bf(lo) | ((unsigned int)f2bf(hi) << 16);
}

// ------- fused prep: embedding + weight transpose/cast + key precompute + dst histogram -------
// deg/bnsum/bmeta are pre-zeroed by one hipMemsetAsync before this kernel.
__global__ void k_prep(const int* __restrict__ x, const float* __restrict__ xe1,
                       const float* __restrict__ xe2, unsigned int* __restrict__ h,
                       const float* __restrict__ W1, const float* __restrict__ W2,
                       unsigned short* __restrict__ w1t, unsigned short* __restrict__ w2t,
                       int* __restrict__ deg,
                       const int* __restrict__ ei, const int* __restrict__ ea,
                       int* __restrict__ keyv) {
    int idx = blockIdx.x * 256 + threadIdx.x;   // [0, (N+1)*64)
    int i = idx >> 6, j = idx & 63;
    if (i < N_NODES) {
        int a = x[2 * i], c = x[2 * i + 1];
        float2 va = *(const float2*)(xe1 + a * EMB + j * 2);
        float2 vb = *(const float2*)(xe2 + c * EMB + j * 2);
        h[i * 64 + j] = packbf(va.x + vb.x, va.y + vb.y);
    } else if (i == N_NODES) {
        h[(size_t)i * 64 + j] = 0u;             // zero sentinel row
    }
    if (idx < 4 * 32768) {                      // weight transpose+cast
        int sec = idx >> 15, q = idx & 32767;
        if (sec < 2) {       // W1[sec]: [128][256] -> w1t[sec][c*128+r]
            int r = q >> 8, c = q & 255;
            w1t[sec * 32768 + c * 128 + r] = f2bf(W1[sec * 32768 + q]);
        } else {             // W2[sec-2]: [256][128] -> w2t[sec-2][c*256+r]
            int s = sec - 2;
            int r = q >> 7, c = q & 127;
            w2t[s * 32768 + c * 256 + r] = f2bf(W2[s * 32768 + q]);
        }
    }
    if (idx < N_EDGES) {                        // packed key + dst histogram
        int2 aa = *(const int2*)(ea + 2 * idx);
        keyv[idx] = (ei[idx] << 5) | (aa.x * 3 + aa.y);
        atomicAdd(&deg[ei[N_EDGES + idx]], 1);
    }
}

// ---------------- CSR region allocation (unordered) + e12@W1 micro-GEMM ----------------
__global__ void k_alloc(const int* __restrict__ deg, int* __restrict__ gcur,
                        int* __restrict__ offs, int* __restrict__ cursor,
                        int* __restrict__ keys, int* __restrict__ bcnt,
                        const float* __restrict__ e1, const float* __restrict__ e2,
                        const float* __restrict__ W1, unsigned short* __restrict__ w1e) {
    __shared__ int wbase[4];
    __shared__ int lc[8];
    int tid = threadIdx.x, lane = tid & 63, wid = tid >> 6;
    if (tid < 8) lc[tid] = 0;
    int i = blockIdx.x * 256 + tid;
    int d = (i < N_NODES) ? deg[i] : 0;
    int pd = (d + 15) & ~15;
    int s = pd;                                  // wave inclusive scan
#pragma unroll
    for (int off = 1; off < 64; off <<= 1) {
        int t = __shfl_up(s, off);
        if (lane >= off) s += t;
    }
    if (lane == 63) wbase[wid] = s;
    __syncthreads();
    if (tid == 0) {                              // one global atomic per block
        int t0 = wbase[0], t1 = wbase[1], t2 = wbase[2], t3 = wbase[3];
        int b = atomicAdd(gcur, t0 + t1 + t2 + t3);
        wbase[0] = b; wbase[1] = b + t0; wbase[2] = b + t0 + t1; wbase[3] = b + t0 + t1 + t2;
    }
    __syncthreads();
    if (i < N_NODES) {
        int o = wbase[wid] + s - pd;             // exclusive within wave
        offs[i] = o;
        cursor[i] = o;
        for (int j = d; j < pd; ++j) keys[o + j] = SENT_KEY;
        int nch = pd >> 4;
        atomicAdd(&lc[nch > 7 ? 7 : nch], 1);
    }
    __syncthreads();
    if (tid < 8) atomicAdd(&bcnt[tid], lc[tid]);

    // e12@W1 micro-GEMM: blocks 0..41 (layer l, combo c); w1e[l][n][32]
    if (blockIdx.x < 42) {
        int l = blockIdx.x / 21, c = blockIdx.x % 21;
        int a0 = c / 3, a1 = c - a0 * 3;
        const float* E1 = e1 + l * 896 + a0 * 128;
        const float* E2 = e2 + l * 384 + a1 * 128;
        const float* w1 = W1 + l * 32768;
        int n = tid;                             // 0..255
        float acc = 0.f;
        for (int k = 0; k < 128; ++k)
            acc = fmaf(E1[k] + E2[k], w1[k * 256 + n], acc);
        w1e[(size_t)l * 8192 + n * 32 + c] = f2bf(acc);
        if (c == 0) {
            for (int cc = 21; cc < 32; ++cc) w1e[(size_t)l * 8192 + n * 32 + cc] = 0;
        }
    }
}

// fill packed keys via keyv gather (XCD-partitioned) + build degree-bucket permutation
__global__ void k_fill(const int* __restrict__ dst, const int* __restrict__ keyv,
                       int* __restrict__ cursor, int* __restrict__ keys,
                       const int* __restrict__ deg, const int* __restrict__ bcnt,
                       int* __restrict__ bcur, int* __restrict__ perm) {
    int xcd = blockIdx.x & 7, chunk = blockIdx.x >> 3;
    int lo = xcd * NODES_PER_XCD, hi = lo + NODES_PER_XCD;
    int e0 = chunk * XCHUNK + threadIdx.x * 4;
#pragma unroll
    for (int it = 0; it < XCHUNK / 1024; ++it) {
        int e = e0 + it * 1024;
        if (e < N_EDGES) {
            int4 d4 = *(const int4*)(dst + e);
            int dv[4] = {d4.x, d4.y, d4.z, d4.w};
#pragma unroll
            for (int q = 0; q < 4; ++q) {
                int d = dv[q];
                if (d >= lo && d < hi) {
                    int p = atomicAdd(&cursor[d], 1);
                    keys[p] = keyv[e + q];
                }
            }
        }
    }
    // degree-bucket counting sort: first PBLK blocks place their 256 nodes
    if (blockIdx.x < PBLK) {
        __shared__ int lcnt[8], gbase[8], tbase[8];
        if (threadIdx.x < 8) lcnt[threadIdx.x] = 0;
        __syncthreads();
        int i = blockIdx.x * 256 + threadIdx.x;
        int b = 0, lrank = 0;
        if (i < N_NODES) {
            int nch = (deg[i] + 15) >> 4;
            b = nch > 7 ? 7 : nch;
            lrank = atomicAdd(&lcnt[b], 1);
        }
        __syncthreads();
        if (threadIdx.x < 8) {
            gbase[threadIdx.x] = atomicAdd(&bcur[threadIdx.x], lcnt[threadIdx.x]);
            int s = 0;
            for (int k = 0; k < threadIdx.x; ++k) s += bcnt[k];
            tbase[threadIdx.x] = s;
        }
        __syncthreads();
        if (i < N_NODES) perm[tbase[b] + gbase[b] + lrank] = i;
    }
}

// ---------------- aggregation: PURE gather-sum (+ layer-0 combo counting) -------------
// Round-10 proven form: VGPR=64, (256,4) — do NOT cap tighter (round-12: (256,8)
// forced VGPR 32, spilled g[8] to scratch, 48->82us). Layer 0 additionally counts
// combos into per-group LDS bins (replaces the k_cnt launch); sentinel keys land
// in bin 21 whose w1e column is zero.
__global__ __launch_bounds__(256, 4) void k_agg(
    const unsigned int* __restrict__ h,        // [(N+1)][64] packed bf16x2 (row N = zeros)
    const int* __restrict__ offs,              // [N] padded region starts (unordered)
    const int* __restrict__ deg,               // [N] real degrees
    const int* __restrict__ keys,              // padded packed keys
    const int* __restrict__ perm,              // degree-bucket-sorted node ids
    unsigned int* __restrict__ agg,            // [NPAD][64] packed bf16x2
    unsigned int* __restrict__ cntb32,         // [NPAD][16] dwords (32 bf16 combo counts)
    int do_cnt)
{
    __shared__ int bins[16][24];
    int wave = threadIdx.x >> 6, lane = threadIdx.x & 63;
    int sub = lane >> 4, fl = lane & 15;
    int grp = threadIdx.x >> 4;                  // 0..15 node-groups per block
    if (do_cnt) {
        for (int t = threadIdx.x; t < 16 * 24; t += 256) ((int*)bins)[t] = 0;
        __syncthreads();
    }
    int wi = blockIdx.x * 4 + wave;              // global wave id in [0, 12544)
    int q = (wi & 255) * 49 + (wi >> 8);         // bijection (12544 = 256*49): spread degrees
    int slot = q * 4 + sub;                      // wave keeps 4 CONSECUTIVE sorted slots
    int node = (slot < N_NODES) ? perm[slot] : slot;
    float ax[8] = {0.f, 0.f, 0.f, 0.f, 0.f, 0.f, 0.f, 0.f};
    int o = 0, nch = 0;
    if (node < N_NODES) {
        o = offs[node];
        nch = (deg[node] + 15) >> 4;
        uint4 hv = *(const uint4*)(h + (size_t)node * 64 + fl * 4);   // self loop
        ax[0] = bflo(hv.x);  ax[1] = bfhi(hv.x);
        ax[2] = bflo(hv.y);  ax[3] = bfhi(hv.y);
        ax[4] = bflo(hv.z);  ax[5] = bfhi(hv.z);
        ax[6] = bflo(hv.w);  ax[7] = bfhi(hv.w);
    }
    int maxch = nch;
#pragma unroll
    for (int d = 32; d; d >>= 1) maxch = max(maxch, __shfl_xor(maxch, d));
    int key = (0 < nch) ? keys[o + fl] : SENT_KEY;
    for (int c = 0; c < maxch; ++c) {
        if (do_cnt && c < nch) atomicAdd(&bins[grp][key & 31], 1);
        int keyn = (c + 1 < nch) ? keys[o + (c + 1) * 16 + fl] : SENT_KEY;
        uint4 g[8];
#pragma unroll
        for (int j = 0; j < 8; ++j) {
            int kj = __shfl(key, sub * 16 + j);
            g[j] = *(const uint4*)(h + (size_t)(kj >> 5) * 64 + fl * 4);
        }
#pragma unroll
        for (int j = 0; j < 8; ++j) {
            uint4 gg = g[j];
            int kb = __shfl(key, sub * 16 + 8 + j);
            g[j] = *(const uint4*)(h + (size_t)(kb >> 5) * 64 + fl * 4);
            ax[0] += bflo(gg.x);  ax[1] += bfhi(gg.x);
            ax[2] += bflo(gg.y);  ax[3] += bfhi(gg.y);
            ax[4] += bflo(gg.z);  ax[5] += bfhi(gg.z);
            ax[6] += bflo(gg.w);  ax[7] += bfhi(gg.w);
        }
#pragma unroll
        for (int j = 0; j < 8; ++j) {
            uint4 gg = g[j];
            ax[0] += bflo(gg.x);  ax[1] += bfhi(gg.x);
            ax[2] += bflo(gg.y);  ax[3] += bfhi(gg.y);
            ax[4] += bflo(gg.z);  ax[5] += bfhi(gg.z);
            ax[6] += bflo(gg.w);  ax[7] += bfhi(gg.w);
        }
        key = keyn;
    }
    {
        uint4 out;
        out.x = packbf(ax[0], ax[1]); out.y = packbf(ax[2], ax[3]);
        out.z = packbf(ax[4], ax[5]); out.w = packbf(ax[6], ax[7]);
        *(uint4*)(agg + (size_t)node * 64 + fl * 4) = out;   // pad rows -> zeros
    }
    if (do_cnt) {
        __syncthreads();
        if (node < NPAD) {
            int c0 = 0, c1 = 0;
            if (node < N_NODES && fl < 11) {
                c0 = bins[grp][2 * fl]     + (fl == 6 ? 1 : 0);   // self loop -> combo 12
                c1 = bins[grp][2 * fl + 1];
            }
            cntb32[(size_t)node * 16 + fl] = packbf((float)c0, (float)c1);
        }
    }
}

// ---------------- fused MLP + BN stats: ALL weights resident in LDS (144 KB), 1 barrier ----------------
// 1024-thread blocks (16 waves x 16 rows = 256 rows/block, grid 196). Stage w1t/w2t/w1e
// once with XOR-swizzle (byte ^= (row&7)<<4 on w1s/w2s -> conflict-free b128 reads),
// then waves run barrier-free.
__global__ __launch_bounds__(1024, 1) void k_mlp(
    unsigned short* aggh2,                     // [NPAD][128] bf16 in, [N][128] bf16 out
    const unsigned short* __restrict__ cntb,   // [NPAD][32] bf16 combo counts
    const unsigned short* __restrict__ w1t,    // [256][128]  (W1 transposed: [n][k])
    const unsigned short* __restrict__ w1e,    // [256][32]   (e12@W1 transposed: [n][c])
    const float* __restrict__ b1,              // [256]
    const unsigned short* __restrict__ w2t,    // [128][256]  (W2 transposed: [n][k])
    const float* __restrict__ b2,              // [128]
    float* __restrict__ bnsum)                 // [256]: cols 0..127 sum, 128..255 sumsq
{
    __shared__ unsigned short w1s[256 * 128];  // 64 KB, XOR-swizzled rows (256 B)
    __shared__ unsigned short w2s[128 * 256];  // 64 KB, XOR-swizzled rows (512 B)
    __shared__ unsigned short w1es[256 * 32];  // 16 KB, linear
    __shared__ float bn[256];
    int tid = threadIdx.x;                     // 0..1023
    int lane = tid & 63;
    int wave = tid >> 6;                       // 0..15
    int quad = lane >> 4, r16 = lane & 15;
    int m0 = (blockIdx.x * 16 + wave) * 16;    // 16 rows per wave
    int sel  = (lane >> 5) & 1;
    int srcA = ((lane >> 4) & 1) * 32 + r16;
    int srcB = srcA + 16;
    if (tid < 256) bn[tid] = 0.f;

    // ---- stage all weights: 9216 16B-chunks over 1024 threads = 9 each ----
#pragma unroll
    for (int it = 0; it < 9; ++it) {
        int ch = it * 1024 + tid;
        if (ch < 4096) {                       // w1s: row=ch>>4 (16 chunks/row)
            int row = ch >> 4, sl = ch & 15;
            uint4 v = *(const uint4*)(w1t + row * 128 + sl * 8);
            int byte = row * 256 + ((sl * 16) ^ ((row & 7) << 4));
            *(uint4*)((char*)w1s + byte) = v;
        } else if (ch < 8192) {                // w2s: 32 chunks/row
            int c = ch - 4096;
            int row = c >> 5, sl = c & 31;
            uint4 v = *(const uint4*)(w2t + row * 256 + sl * 8);
            int byte = row * 512 + ((sl * 16) ^ ((row & 7) << 4));
            *(uint4*)((char*)w2s + byte) = v;
        } else {                               // w1es: linear, 4 chunks/row
            int c = ch - 8192;
            int row = c >> 2, sl = c & 3;
            *(uint4*)(w1es + row * 32 + sl * 8) = *(const uint4*)(w1e + row * 32 + sl * 8);
        }
    }

    // agg B-frags (GEMM1 swapped): B[k=quad*8+j][node=r16]; chunk 4 = cnt (K 128..159)
    short8 bagg[5];
#pragma unroll
    for (int c = 0; c < 4; ++c)
        bagg[c] = *(const short8*)(aggh2 + (size_t)(m0 + r16) * 128 + c * 32 + quad * 8);
    bagg[4] = *(const short8*)(cntb + (size_t)(m0 + r16) * 32 + quad * 8);

    float b2v[8];
#pragma unroll
    for (int n = 0; n < 8; ++n) b2v[n] = b2[n * 16 + r16];

    __syncthreads();                           // weights + bn init visible

    f32x4 acc2[8];
#pragma unroll
    for (int n = 0; n < 8; ++n) acc2[n] = (f32x4){0.f, 0.f, 0.f, 0.f};

    int swz = (r16 & 7) << 4;                  // read-side XOR (row&7 == r16&7)
    for (int c2 = 0; c2 < 8; ++c2) {
        unsigned int pk[2][2];                 // [ntl][dword]
#pragma unroll
        for (int ntl = 0; ntl < 2; ++ntl) {
            int nt = c2 * 2 + ntl;
            int row = nt * 16 + r16;
            short8 aw[5];
#pragma unroll
            for (int c = 0; c < 4; ++c)
                aw[c] = *(const short8*)((char*)w1s + row * 256 + ((c * 64 + quad * 16) ^ swz));
            aw[4] = *(const short8*)(w1es + row * 32 + quad * 8);
            float4 bv = *(const float4*)(b1 + nt * 16 + quad * 4);
            f32x4 a1a = {0.f, 0.f, 0.f, 0.f}, a1b = {0.f, 0.f, 0.f, 0.f};
            a1a = __builtin_amdgcn_mfma_f32_16x16x32_bf16(aw[0], bagg[0], a1a, 0, 0, 0);
            a1b = __builtin_amdgcn_mfma_f32_16x16x32_bf16(aw[1], bagg[1], a1b, 0, 0, 0);
            a1a = __builtin_amdgcn_mfma_f32_16x16x32_bf16(aw[2], bagg[2], a1a, 0, 0, 0);
            a1b = __builtin_amdgcn_mfma_f32_16x16x32_bf16(aw[3], bagg[3], a1b, 0, 0, 0);
            a1a = __builtin_amdgcn_mfma_f32_16x16x32_bf16(aw[4], bagg[4], a1a, 0, 0, 0);
            float v0 = a1a[0] + a1b[0] + bv.x; v0 = v0 > 0.f ? v0 : 0.f;
            float v1 = a1a[1] + a1b[1] + bv.y; v1 = v1 > 0.f ? v1 : 0.f;
            float v2 = a1a[2] + a1b[2] + bv.z; v2 = v2 > 0.f ? v2 : 0.f;
            float v3 = a1a[3] + a1b[3] + bv.w; v3 = v3 > 0.f ? v3 : 0.f;
            pk[ntl][0] = packbf(v0, v1);
            pk[ntl][1] = packbf(v2, v3);
        }
        short8 a2f;
        {
            int u0 = __shfl((int)pk[0][0], srcA), w0 = __shfl((int)pk[1][0], srcA);
            int u1 = __shfl((int)pk[0][1], srcA), w1_ = __shfl((int)pk[1][1], srcA);
            int u2 = __shfl((int)pk[0][0], srcB), w2_ = __shfl((int)pk[1][0], srcB);
            int u3 = __shfl((int)pk[0][1], srcB), w3_ = __shfl((int)pk[1][1], srcB);
            union { int i[4]; short8 s; } a2u;
            a2u.i[0] = sel ? w0 : u0;
            a2u.i[1] = sel ? w1_ : u1;
            a2u.i[2] = sel ? w2_ : u2;
            a2u.i[3] = sel ? w3_ : u3;
            a2f = a2u.s;
        }
#pragma unroll
        for (int n = 0; n < 8; ++n) {
            int row = n * 16 + r16;
            short8 bw = *(const short8*)((char*)w2s + row * 512 + ((c2 * 64 + quad * 16) ^ swz));
            acc2[n] = __builtin_amdgcn_mfma_f32_16x16x32_bf16(a2f, bw, acc2[n], 0, 0, 0);
        }
    }
    // epilogue: store h2 + accumulate per-lane BN partial sums (fp32, rows < N only)
    float s[8], q[8];
#pragma unroll
    for (int n = 0; n < 8; ++n) { s[n] = 0.f; q[n] = 0.f; }
#pragma unroll
    for (int n = 0; n < 8; ++n)
#pragma unroll
        for (int r = 0; r < 4; ++r) {
            int row = m0 + quad * 4 + r;
            float v = acc2[n][r] + b2v[n];
            if (row < N_NODES) {
                aggh2[(size_t)row * 128 + n * 16 + r16] = f2bf(v);
                s[n] += v; q[n] += v * v;
            }
        }
    // reduce over quads (same col set): lanes differ in bits 4,5
#pragma unroll
    for (int n = 0; n < 8; ++n) {
        s[n] += __shfl_xor(s[n], 16); q[n] += __shfl_xor(q[n], 16);
        s[n] += __shfl_xor(s[n], 32); q[n] += __shfl_xor(q[n], 32);
    }
    if (quad == 0) {          // 16 lanes per wave x 16 waves -> LDS atomics
#pragma unroll
        for (int n = 0; n < 8; ++n) {
            atomicAdd(&bn[n * 16 + r16], s[n]);
            atomicAdd(&bn[128 + n * 16 + r16], q[n]);
        }
    }
    __syncthreads();
    if (tid < 256) atomicAdd(&bnsum[tid], bn[tid]);   // one device atomic per col
}

// ---------------- BN finalize + apply (fused; +relu for layer 0 -> bf16 h; layer 1 -> fp32 out) ----------------
__global__ void k_bnnorm(const uint4* __restrict__ h2, const float* __restrict__ bnsum,
                         const float* __restrict__ gamma, const float* __restrict__ beta,
                         uint4* __restrict__ outb, float4* __restrict__ outf, int mode) {
    __shared__ float ab[256];
    int tid = threadIdx.x;
    if (tid < 128) {
        float mean = bnsum[tid] * (1.f / N_NODES);
        float var  = bnsum[128 + tid] * (1.f / N_NODES) - mean * mean;
        float rstd = rsqrtf(var + BN_EPS);
        float g = gamma[tid];
        ab[tid]       = g * rstd;                       // scale
        ab[128 + tid] = beta[tid] - mean * g * rstd;    // shift
    }
    __syncthreads();
    int idx = blockIdx.x * 256 + tid;          // [0, N*16) uint4 units (8 channels each)
    if (idx >= N_NODES * 16) return;
    int p = (idx & 15) * 8;                    // starting channel
    uint4 hv = h2[idx];
    float v0 = bflo(hv.x) * ab[p + 0] + ab[128 + p + 0];
    float v1 = bfhi(hv.x) * ab[p + 1] + ab[128 + p + 1];
    float v2 = bflo(hv.y) * ab[p + 2] + ab[128 + p + 2];
    float v3 = bfhi(hv.y) * ab[p + 3] + ab[128 + p + 3];
    float v4 = bflo(hv.z) * ab[p + 4] + ab[128 + p + 4];
    float v5 = bfhi(hv.z) * ab[p + 5] + ab[128 + p + 5];
    float v6 = bflo(hv.w) * ab[p + 6] + ab[128 + p + 6];
    float v7 = bfhi(hv.w) * ab[p + 7] + ab[128 + p + 7];
    if (mode == 0) {
        v0 = v0 > 0.f ? v0 : 0.f; v1 = v1 > 0.f ? v1 : 0.f;
        v2 = v2 > 0.f ? v2 : 0.f; v3 = v3 > 0.f ? v3 : 0.f;
        v4 = v4 > 0.f ? v4 : 0.f; v5 = v5 > 0.f ? v5 : 0.f;
        v6 = v6 > 0.f ? v6 : 0.f; v7 = v7 > 0.f ? v7 : 0.f;
        uint4 out;
        out.x = packbf(v0, v1); out.y = packbf(v2, v3);
        out.z = packbf(v4, v5); out.w = packbf(v6, v7);
        outb[idx] = out;
    } else {
        outf[2 * idx]     = make_float4(v0, v1, v2, v3);
        outf[2 * idx + 1] = make_float4(v4, v5, v6, v7);
    }
}

extern "C" void kernel_launch(void* const* d_in, const int* in_sizes, int n_in,
                              void* d_out, int out_size, void* d_ws, size_t ws_size,
                              hipStream_t stream) {
    const int* x  = (const int*)d_in[0];
    const int* ei = (const int*)d_in[1];
    const int* ea = (const int*)d_in[2];
    // d_in[3] = batch (unused)
    const float* xe1 = (const float*)d_in[4];
    const float* xe2 = (const float*)d_in[5];
    const float* e1  = (const float*)d_in[6];   // [2][7][128]
    const float* e2  = (const float*)d_in[7];   // [2][3][128]
    const float* W1  = (const float*)d_in[8];   // [2][128][256]
    const float* b1  = (const float*)d_in[9];   // [2][256]
    const float* W2  = (const float*)d_in[10];  // [2][256][128]
    const float* b2  = (const float*)d_in[11];  // [2][128]
    const float* gm  = (const float*)d_in[12];  // [2][128]
    const float* bt  = (const float*)d_in[13];  // [2][128]

    char* ws = (char*)d_ws;
    size_t off = 0;
    auto take = [&](size_t bytes) -> char* {
        char* p = ws + off;
        off = (off + bytes + 255) & ~(size_t)255;
        return p;
    };
    unsigned int* h_buf = (unsigned int*)take((size_t)(N_NODES + 1) * 64 * 4); // +1 zero row
    unsigned int* aggb  = (unsigned int*)take((size_t)NPAD * 64 * 4);          // agg, then h2
    unsigned short* w1t = (unsigned short*)take((size_t)2 * 32768 * 2);
    unsigned short* w2t = (unsigned short*)take((size_t)2 * 32768 * 2);
    unsigned short* w1e = (unsigned short*)take((size_t)2 * 8192 * 2);         // [2][256][32]
    unsigned int* cntb32 = (unsigned int*)take((size_t)NPAD * 16 * 4);         // [NPAD][32] bf16
    // combined zero-init region: deg[50000] | bnsum[512] | bmeta[32]
    int* zbuf   = (int*)take((size_t)(N_NODES + 512 + 32) * 4);
    int* deg    = zbuf;
    float* bnsum = (float*)(zbuf + N_NODES);            // [2][256]
    int* bmeta  = zbuf + N_NODES + 512;                 // bcnt[8], bcur[8], gcur[1]
    int* offs   = (int*)take((size_t)(N_NODES + 1) * 4);
    int* cursor = (int*)take((size_t)N_NODES * 4);
    int* keys   = (int*)take((size_t)(N_EDGES + N_NODES * 16) * 4);
    int* keyv   = (int*)take((size_t)N_EDGES * 4);
    int* perm   = (int*)take((size_t)N_NODES * 4);
    int* bcnt = bmeta, *bcur = bmeta + 8, *gcur = bmeta + 16;

    hipMemsetAsync(zbuf, 0, (size_t)(N_NODES + 512 + 32) * 4, stream);
    k_prep<<<((N_NODES + 1) * 64 + 255) / 256, 256, 0, stream>>>(x, xe1, xe2, h_buf,
                                                                 W1, W2, w1t, w2t, deg,
                                                                 ei, ea, keyv);
    k_alloc<<<PBLK, 256, 0, stream>>>(deg, gcur, offs, cursor, keys, bcnt,
                                      e1, e2, W1, w1e);
    k_fill<<<8 * NCHUNKS, 256, 0, stream>>>(ei + N_EDGES, keyv, cursor, keys,
                                            deg, bcnt, bcur, perm);

    for (int l = 0; l < 2; ++l) {
        k_agg<<<NPAD / 16, 256, 0, stream>>>(h_buf, offs, deg, keys, perm, aggb,
                                             cntb32, l == 0 ? 1 : 0);
        k_mlp<<<NPAD / 256, 1024, 0, stream>>>((unsigned short*)aggb, (const unsigned short*)cntb32,
                                               w1t + l * 32768, w1e + l * 8192, b1 + l * 256,
                                               w2t + l * 32768, b2 + l * 128, bnsum + l * 256);
        k_bnnorm<<<(N_NODES * 16 + 255) / 256, 256, 0, stream>>>((const uint4*)aggb, bnsum + l * 256,
                                                                 gm + l * 128, bt + l * 128,
                                                                 (uint4*)h_buf, (float4*)d_out, l);
    }
}